// Round 3
// baseline (275.029 us; speedup 1.0000x reference)
//
#include <hip/hip_runtime.h>

// Problem constants (match reference)
#define BATCH 32
#define T_IN 1024
#define TP 1025      // T+1 (phoneme + silence token)
#define EMB 384
#define GROUPS 4
#define GC 96        // channels per group

typedef __attribute__((ext_vector_type(8))) short short8;   // 8 bf16 (4 VGPRs)
typedef __attribute__((ext_vector_type(4))) float f32x4;    // 4 fp32 acc

#define N_WPACK (GROUPS * 9 * 6 * 64 * 8)   // 110592 bf16 elements

__device__ __forceinline__ unsigned short f2bf(float f) {
    union { float f; unsigned u; } v; v.f = f;
    unsigned u = v.u + 0x7fffu + ((v.u >> 16) & 1u);  // RNE
    return (unsigned short)(u >> 16);
}

// ---------------------------------------------------------------------------
// Kernel 0 (prep): pack w1 -> bf16 MFMA B-fragment layout.
// Flat index i = ((g*9 + ks)*6 + nt)*512 + lane*8 + j
//   oc = nt*16 + (lane&15); kk = ks*32 + (lane>>4)*8 + j; k = kk/96, ic = kk%96
// ---------------------------------------------------------------------------
__global__ __launch_bounds__(256) void prep_kernel(const float* __restrict__ w1,
                                                   unsigned short* __restrict__ wpack) {
    int i = blockIdx.x * 256 + threadIdx.x;
    if (i >= N_WPACK) return;
    int j = i & 7;
    int lane = (i >> 3) & 63;
    int rest = i >> 9;
    int nt = rest % 6; rest /= 6;
    int ks = rest % 9;
    int g = rest / 9;
    int oc = nt * 16 + (lane & 15);
    int kk = ks * 32 + (lane >> 4) * 8 + j;
    int k = kk / 96, ic = kk % 96;
    wpack[i] = f2bf(w1[((size_t)(g * GC + oc) * GC + ic) * 3 + k]);
}

// ---------------------------------------------------------------------------
// Kernel 1: per-batch cumsum (wave 0) + direct scatter of frame->token index.
// idx[b][t] = token j for cum[j-1] <= t < cum[j]; 0xFFFF past total.
// Eliminates all binary searches in the gather.
// ---------------------------------------------------------------------------
__global__ __launch_bounds__(256) void scan_scatter_kernel(const int* __restrict__ dur,
                                                           unsigned short* __restrict__ idx,
                                                           int t_out) {
    const int b = blockIdx.x;
    const int tid = threadIdx.x;
    __shared__ int scum[TP];

    if (tid < 64) {
        const int* d = dur + b * TP;
        int offset = 0;
        for (int r = 0; r < 17; ++r) {
            int i2 = r * 64 + tid;
            int v = (i2 < TP) ? d[i2] : 0;
            int s = v;
#pragma unroll
            for (int off = 1; off < 64; off <<= 1) {
                int n = __shfl_up(s, off, 64);
                if (tid >= off) s += n;
            }
            if (i2 < TP) scum[i2] = s + offset;
            offset += __shfl(s, 63, 64);
        }
    }
    __syncthreads();

    unsigned short* ib = idx + (size_t)b * t_out;
    for (int j = tid; j < TP; j += 256) {
        int c = scum[j];
        int d = dur[b * TP + j];
        for (int f = c - d; f < c; ++f) ib[f] = (unsigned short)j;
    }
    const int total = scum[TP - 1];
    for (int t = total + tid; t < t_out; t += 256) ib[t] = 0xFFFFu;
}

// ---------------------------------------------------------------------------
// Kernel 2: grouped conv (k=3,pad 1) + ReLU + 1x1 conv via bf16 MFMA.
// grid = (17 t-tiles of 64, 32 batches), block = 256 (4 waves = 4 groups).
// Wave g: 4x6 MFMA register tile (64 t-rows x 96 oc of group g):
//   per kstep: 4 ds_read_b128 A-frags + 6 coalesced 16B B-frags + 24 MFMAs.
// LDS x-tile row stride 392 shorts = 196 dwords; start banks 4*(49*lr+q)%32
// give uniform 2-per-bank load within 16-lane phases -> effectively free.
// Epilogue: shuffle-reduce across lr, cross-group sum in LDS -> pred direct
// (no atomics, no init pass).
// ---------------------------------------------------------------------------
__global__ __launch_bounds__(256) void conv_mfma_kernel(const float* __restrict__ phoneme,
                                                        const float* __restrict__ silence,
                                                        const float* __restrict__ b1,
                                                        const float* __restrict__ w2,
                                                        const float* __restrict__ b2,
                                                        const unsigned short* __restrict__ wpack,
                                                        float* __restrict__ pred) {
    const int tile = blockIdx.x;
    const int b = blockIdx.y;
    const int t0 = tile * 64;

    __shared__ __align__(16) unsigned short xs[66][392];  // rows t0-1..t0+64, all 384 ch
    __shared__ float red[4][64];

    const int tid = threadIdx.x;

    // Stage 66 full rows (fp32 -> bf16), coalesced 1536B-row float4 reads
    for (int e = tid; e < 66 * 96; e += 256) {
        int row = e / 96;
        int v = e - row * 96;
        int r = t0 - 1 + row;
        float4 val;
        if (r < 0 || r > T_IN) {
            val = make_float4(0.f, 0.f, 0.f, 0.f);
        } else if (r == T_IN) {
            val = *(const float4*)(silence + v * 4);
        } else {
            val = *(const float4*)(phoneme + ((size_t)(b * T_IN + r)) * EMB + v * 4);
        }
        ushort4 pk;
        pk.x = f2bf(val.x); pk.y = f2bf(val.y); pk.z = f2bf(val.z); pk.w = f2bf(val.w);
        *(ushort4*)&xs[row][v * 4] = pk;
    }
    __syncthreads();

    const int g = tid >> 6;     // wave = group
    const int lane = tid & 63;
    const int quad = lane >> 4;
    const int lr = lane & 15;

    f32x4 acc[4][6];
#pragma unroll
    for (int mt = 0; mt < 4; ++mt)
#pragma unroll
        for (int nt = 0; nt < 6; ++nt) acc[mt][nt] = (f32x4){0.f, 0.f, 0.f, 0.f};

    const unsigned short* wg = wpack + (size_t)g * 9 * 6 * 512;

#pragma unroll
    for (int ks = 0; ks < 9; ++ks) {
        const int tap = ks / 3;                               // kstep-uniform
        const int col = g * GC + 32 * (ks % 3) + quad * 8;    // channel offset
        short8 a[4];
#pragma unroll
        for (int mt = 0; mt < 4; ++mt)
            a[mt] = *(const short8*)&xs[mt * 16 + lr + tap][col];
#pragma unroll
        for (int nt = 0; nt < 6; ++nt) {
            short8 bf = *(const short8*)(wg + ((size_t)(ks * 6 + nt) * 64 + lane) * 8);
#pragma unroll
            for (int mt = 0; mt < 4; ++mt)
                acc[mt][nt] = __builtin_amdgcn_mfma_f32_16x16x32_bf16(a[mt], bf, acc[mt][nt], 0, 0, 0);
        }
    }

    // Epilogue: bias + ReLU + w2-dot partials; m = mt*16 + quad*4 + reg, oc col = lr
    float s[4][4];
#pragma unroll
    for (int mt = 0; mt < 4; ++mt)
#pragma unroll
        for (int reg = 0; reg < 4; ++reg) s[mt][reg] = 0.f;
#pragma unroll
    for (int nt = 0; nt < 6; ++nt) {
        int oc = g * GC + nt * 16 + lr;
        float bias = b1[oc];
        float wc = w2[oc];
#pragma unroll
        for (int mt = 0; mt < 4; ++mt)
#pragma unroll
            for (int reg = 0; reg < 4; ++reg) {
                float h = acc[mt][nt][reg] + bias;
                h = h > 0.f ? h : 0.f;
                s[mt][reg] += wc * h;
            }
    }
    // butterfly-sum across the 16 lr lanes (stays within each 16-lane group)
#pragma unroll
    for (int off = 1; off < 16; off <<= 1)
#pragma unroll
        for (int mt = 0; mt < 4; ++mt)
#pragma unroll
            for (int reg = 0; reg < 4; ++reg)
                s[mt][reg] += __shfl_xor(s[mt][reg], off, 64);
    // lane lr == mt*4+reg publishes red[g][m]
#pragma unroll
    for (int mt = 0; mt < 4; ++mt)
#pragma unroll
        for (int reg = 0; reg < 4; ++reg)
            if (lr == mt * 4 + reg) red[g][mt * 16 + quad * 4 + reg] = s[mt][reg];
    __syncthreads();

    if (tid < 64) {
        int t = t0 + tid;
        if (t < TP)
            pred[b * TP + t] = red[0][tid] + red[1][tid] + red[2][tid] + red[3][tid] + b2[0];
    }
}

// ---------------------------------------------------------------------------
// Kernel 3: streaming gather via precomputed idx. One float4 per thread,
// no LDS, no sync. grid = (ceil(t_out*96/256), 32).
// ---------------------------------------------------------------------------
__global__ __launch_bounds__(256) void gather_kernel(const float* __restrict__ phoneme,
                                                     const float* __restrict__ silence,
                                                     const unsigned short* __restrict__ idx,
                                                     float* __restrict__ out,
                                                     int t_out) {
    const int b = blockIdx.y;
    const int nfe = t_out * 96;
    int e = blockIdx.x * 256 + threadIdx.x;
    if (e >= nfe) return;
    int fl = e / 96;
    int v = e - fl * 96;
    unsigned short id = idx[(size_t)b * t_out + fl];
    float4 val;
    if (id == 0xFFFFu) {
        val = make_float4(0.f, 0.f, 0.f, 0.f);
    } else if (id == T_IN) {
        val = ((const float4*)silence)[v];
    } else {
        val = ((const float4*)phoneme)[((size_t)b * T_IN + id) * 96 + v];
    }
    ((float4*)out)[(size_t)b * nfe + e] = val;
}

// ---------------------------------------------------------------------------
extern "C" void kernel_launch(void* const* d_in, const int* in_sizes, int n_in,
                              void* d_out, int out_size, void* d_ws, size_t ws_size,
                              hipStream_t stream) {
    const float* phoneme = (const float*)d_in[0];
    const float* silence = (const float*)d_in[1];
    const float* conv1_w = (const float*)d_in[2];
    const float* conv1_b = (const float*)d_in[3];
    const float* conv2_w = (const float*)d_in[4];
    const float* conv2_b = (const float*)d_in[5];
    const int* durations = (const int*)d_in[6];
    // d_in[7] = t_out on device; derive from out_size host-side instead.
    const int t_out = (out_size - BATCH * TP) / (BATCH * EMB);

    float* out_expanded = (float*)d_out;                            // [B, t_out, EMB]
    float* out_pred = (float*)d_out + (size_t)BATCH * t_out * EMB;  // [B, TP]

    // Workspace: idx [B][t_out] ushort, then wpack (16B-aligned)
    unsigned short* idx = (unsigned short*)d_ws;
    size_t idx_bytes = ((size_t)BATCH * t_out * sizeof(unsigned short) + 255) & ~(size_t)255;
    unsigned short* wpack = (unsigned short*)((char*)d_ws + idx_bytes);

    prep_kernel<<<(N_WPACK + 255) / 256, 256, 0, stream>>>(conv1_w, wpack);
    scan_scatter_kernel<<<BATCH, 256, 0, stream>>>(durations, idx, t_out);
    conv_mfma_kernel<<<dim3(17, BATCH), 256, 0, stream>>>(
        phoneme, silence, conv1_b, conv2_w, conv2_b, wpack, out_pred);
    gather_kernel<<<dim3((t_out * 96 + 255) / 256, BATCH), 256, 0, stream>>>(
        phoneme, silence, idx, out_expanded, t_out);
}